// Round 1
// baseline (541.878 us; speedup 1.0000x reference)
//
#include <hip/hip_runtime.h>

#define NCTX 4096
#define DMODEL 2048
#define DHEAD 128

typedef short s16x8 __attribute__((ext_vector_type(8)));
typedef float f32x4 __attribute__((ext_vector_type(4)));
typedef unsigned short u16;

__device__ __forceinline__ u16 f2bf(float f) {
  union { float f; unsigned u; } v; v.f = f;
  unsigned u = v.u;
  return (u16)((u + 0x7FFFu + ((u >> 16) & 1u)) >> 16);
}

__device__ __forceinline__ void gl_lds16(const void* g, void* l) {
  __builtin_amdgcn_global_load_lds((const __attribute__((address_space(1))) void*)g,
                                   (__attribute__((address_space(3))) void*)l, 16, 0, 0);
}

// ---------------- elementwise fp32 -> bf16 cast (float4 / ushort4) ----------------
__global__ __launch_bounds__(256) void cast_f32_bf16(const float* __restrict__ in,
                                                     u16* __restrict__ out, int n4) {
  int i = blockIdx.x * 256 + threadIdx.x;
  if (i >= n4) return;
  float4 v = ((const float4*)in)[i];
  ushort4 o;
  o.x = f2bf(v.x); o.y = f2bf(v.y); o.z = f2bf(v.z); o.w = f2bf(v.w);
  ((ushort4*)out)[i] = o;
}

// ---------------- x [4096,2048] fp32 -> xT [2048,4096] bf16 ----------------
__global__ __launch_bounds__(256) void transpose_cast(const float* __restrict__ X,
                                                      u16* __restrict__ XT) {
  __shared__ float tile[64][65];
  int db = blockIdx.x * 64, mb = blockIdx.y * 64;
  int tx = threadIdx.x & 63, ty = threadIdx.x >> 6;
#pragma unroll
  for (int r = 0; r < 16; ++r) {
    int row = ty * 16 + r;
    tile[row][tx] = X[(size_t)(mb + row) * DMODEL + db + tx];
  }
  __syncthreads();
#pragma unroll
  for (int r = 0; r < 16; ++r) {
    int row = ty * 16 + r;
    XT[(size_t)(db + row) * NCTX + mb + tx] = f2bf(tile[tx][row]);
  }
}

// ---------------- q/k projection, fp32 VALU GEMM ----------------
// O[m,n] = sum_k X[m,k] * W[n,k];  BM=16, BN=128, BK=32; grid (M/16, 2)
__global__ __launch_bounds__(256) void qk_proj(const float* __restrict__ X,
                                               const float* __restrict__ Wq,
                                               const float* __restrict__ Wk,
                                               float* __restrict__ Q,
                                               float* __restrict__ Kout) {
  const float* W = blockIdx.y ? Wk : Wq;
  float* O = blockIdx.y ? Kout : Q;
  int m0 = blockIdx.x * 16;
  __shared__ float xsT[32][16];   // [k][m]
  __shared__ float wsT[32][128];  // [k][n]
  int t = threadIdx.x;
  int tm = t >> 5, tn = t & 31;
  float acc[8] = {0.f, 0.f, 0.f, 0.f, 0.f, 0.f, 0.f, 0.f};
  for (int kt = 0; kt < DMODEL; kt += 32) {
    if (t < 128) {
      int row = t >> 3, c = t & 7;
      float4 v = *(const float4*)(X + (size_t)(m0 + row) * DMODEL + kt + c * 4);
      xsT[c * 4 + 0][row] = v.x; xsT[c * 4 + 1][row] = v.y;
      xsT[c * 4 + 2][row] = v.z; xsT[c * 4 + 3][row] = v.w;
    }
#pragma unroll
    for (int p = 0; p < 4; ++p) {
      int lin = p * 256 + t;
      int row = lin >> 3, c = lin & 7;
      float4 v = *(const float4*)(W + (size_t)row * DMODEL + kt + c * 4);
      wsT[c * 4 + 0][row] = v.x; wsT[c * 4 + 1][row] = v.y;
      wsT[c * 4 + 2][row] = v.z; wsT[c * 4 + 3][row] = v.w;
    }
    __syncthreads();
#pragma unroll
    for (int kk = 0; kk < 32; ++kk) {
      float a0 = xsT[kk][tm * 2 + 0];
      float a1 = xsT[kk][tm * 2 + 1];
      const float* bp = &wsT[kk][tn * 4];
      float b0 = bp[0], b1 = bp[1], b2 = bp[2], b3 = bp[3];
      acc[0] += a0 * b0; acc[1] += a0 * b1; acc[2] += a0 * b2; acc[3] += a0 * b3;
      acc[4] += a1 * b0; acc[5] += a1 * b1; acc[6] += a1 * b2; acc[7] += a1 * b3;
    }
    __syncthreads();
  }
  float4 r0 = make_float4(acc[0], acc[1], acc[2], acc[3]);
  float4 r1 = make_float4(acc[4], acc[5], acc[6], acc[7]);
  *(float4*)(O + (size_t)(m0 + tm * 2 + 0) * DHEAD + tn * 4) = r0;
  *(float4*)(O + (size_t)(m0 + tm * 2 + 1) * DHEAD + tn * 4) = r1;
}

// ---------------- scores = q @ k.T (fp32, causal tiles only) ----------------
// 64x64 tiles, K=128 fully resident; grid (64, 64), skip bj > bi
__global__ __launch_bounds__(256) void scores_kernel(const float* __restrict__ Q,
                                                     const float* __restrict__ Kp,
                                                     float* __restrict__ S) {
  int bj = blockIdx.x, bi = blockIdx.y;
  if (bj > bi) return;
  int m0 = bi * 64, n0 = bj * 64;
  __shared__ float qsT[128][64];  // [d][m]
  __shared__ float ksT[128][64];  // [d][n]
  int t = threadIdx.x;
#pragma unroll
  for (int p = 0; p < 8; ++p) {
    int lin = p * 256 + t;
    int row = lin >> 5, c = lin & 31;
    float4 v = *(const float4*)(Q + (size_t)(m0 + row) * DHEAD + c * 4);
    qsT[c * 4 + 0][row] = v.x; qsT[c * 4 + 1][row] = v.y;
    qsT[c * 4 + 2][row] = v.z; qsT[c * 4 + 3][row] = v.w;
    float4 u = *(const float4*)(Kp + (size_t)(n0 + row) * DHEAD + c * 4);
    ksT[c * 4 + 0][row] = u.x; ksT[c * 4 + 1][row] = u.y;
    ksT[c * 4 + 2][row] = u.z; ksT[c * 4 + 3][row] = u.w;
  }
  __syncthreads();
  int tm = t >> 4, tn = t & 15;
  float acc[4][4] = {};
#pragma unroll 4
  for (int d = 0; d < 128; ++d) {
    float4 a = *(const float4*)&qsT[d][tm * 4];
    float4 b = *(const float4*)&ksT[d][tn * 4];
    acc[0][0] += a.x * b.x; acc[0][1] += a.x * b.y; acc[0][2] += a.x * b.z; acc[0][3] += a.x * b.w;
    acc[1][0] += a.y * b.x; acc[1][1] += a.y * b.y; acc[1][2] += a.y * b.z; acc[1][3] += a.y * b.w;
    acc[2][0] += a.z * b.x; acc[2][1] += a.z * b.y; acc[2][2] += a.z * b.z; acc[2][3] += a.z * b.w;
    acc[3][0] += a.w * b.x; acc[3][1] += a.w * b.y; acc[3][2] += a.w * b.z; acc[3][3] += a.w * b.w;
  }
#pragma unroll
  for (int ii = 0; ii < 4; ++ii) {
    float4 r = make_float4(acc[ii][0], acc[ii][1], acc[ii][2], acc[ii][3]);
    *(float4*)(S + (size_t)(m0 + tm * 4 + ii) * NCTX + n0 + tn * 4) = r;
  }
}

// ---------------- row softmax (fp32) -> bf16 attn, zero-fill j > i ----------------
__global__ __launch_bounds__(256) void softmax_rows(const float* __restrict__ S,
                                                    u16* __restrict__ P) {
  int i = blockIdx.x;
  int t = threadIdx.x;
  __shared__ float rowbuf[NCTX];
  __shared__ float red[4];
  __shared__ float red2[4];
  const float* srow = S + (size_t)i * NCTX;
  int len = i + 1;
  float mx = -3.0e38f;
  for (int j = t; j < len; j += 256) {
    float v = srow[j];
    rowbuf[j] = v;
    mx = fmaxf(mx, v);
  }
#pragma unroll
  for (int o = 32; o > 0; o >>= 1) mx = fmaxf(mx, __shfl_xor(mx, o, 64));
  if ((t & 63) == 0) red[t >> 6] = mx;
  __syncthreads();
  mx = fmaxf(fmaxf(red[0], red[1]), fmaxf(red[2], red[3]));
  float sum = 0.f;
  for (int j = t; j < len; j += 256) sum += __expf(rowbuf[j] - mx);
#pragma unroll
  for (int o = 32; o > 0; o >>= 1) sum += __shfl_xor(sum, o, 64);
  if ((t & 63) == 0) red2[t >> 6] = sum;
  __syncthreads();
  float inv = 1.0f / (red2[0] + red2[1] + red2[2] + red2[3]);
  u16* prow = P + (size_t)i * NCTX;
  for (int j = t; j < NCTX; j += 256) {
    float v = (j < len) ? __expf(rowbuf[j] - mx) * inv : 0.0f;
    prow[j] = f2bf(v);
  }
}

// ---------------- bf16 MFMA GEMM, B^T layout ----------------
// C[M,N] fp32 = A[M,K] (bf16 row-major) * B[N,K]^T (bf16 row-major).
// BM=BN=128, BK=32; 256 threads = 4 waves in 2x2; wave does 4x4 frags of 16x16x32.
// causal: limit K to (bm+1)*128 (query rows m0..m0+127 attend keys <= m0+127).
__global__ __launch_bounds__(256) void gemm_bt(const u16* __restrict__ A,
                                               const u16* __restrict__ B,
                                               float* __restrict__ C,
                                               int M, int N, int K, int causal) {
  __shared__ __align__(16) u16 As[128 * 32];
  __shared__ __align__(16) u16 Bs[128 * 32];
  int t = threadIdx.x;
  int lane = t & 63, w = t >> 6;
  int bm = blockIdx.x, bn = blockIdx.y;
  int m0 = bm * 128, n0 = bn * 128;
  int kEnd = K;
  if (causal) { int ke = (bm + 1) * 128; kEnd = ke < K ? ke : K; }
  int wm = (w >> 1) * 64, wn = (w & 1) * 64;
  int mfrag = lane & 15, quad = lane >> 4;
  int srow = t >> 2, schunk = t & 3;
  f32x4 acc[4][4] = {};
  for (int kt = 0; kt < kEnd; kt += 32) {
#pragma unroll
    for (int p = 0; p < 2; ++p) {
      int row = p * 64 + srow;
      gl_lds16(A + (size_t)(m0 + row) * K + kt + schunk * 8, As + (size_t)(p * 256 + t) * 8);
      gl_lds16(B + (size_t)(n0 + row) * K + kt + schunk * 8, Bs + (size_t)(p * 256 + t) * 8);
    }
    __syncthreads();
    s16x8 af[4], bfr[4];
#pragma unroll
    for (int i = 0; i < 4; ++i)
      af[i] = *(const s16x8*)(As + (wm + i * 16 + mfrag) * 32 + quad * 8);
#pragma unroll
    for (int j = 0; j < 4; ++j)
      bfr[j] = *(const s16x8*)(Bs + (wn + j * 16 + mfrag) * 32 + quad * 8);
#pragma unroll
    for (int i = 0; i < 4; ++i)
#pragma unroll
      for (int j = 0; j < 4; ++j)
        acc[i][j] = __builtin_amdgcn_mfma_f32_16x16x32_bf16(af[i], bfr[j], acc[i][j], 0, 0, 0);
    __syncthreads();
  }
#pragma unroll
  for (int i = 0; i < 4; ++i)
#pragma unroll
    for (int j = 0; j < 4; ++j)
#pragma unroll
      for (int rr = 0; rr < 4; ++rr) {
        int row = m0 + wm + i * 16 + quad * 4 + rr;
        int col = n0 + wn + j * 16 + mfrag;
        C[(size_t)row * N + col] = acc[i][j][rr];
      }
}

extern "C" void kernel_launch(void* const* d_in, const int* in_sizes, int n_in,
                              void* d_out, int out_size, void* d_ws, size_t ws_size,
                              hipStream_t stream) {
  const float* x  = (const float*)d_in[0];
  const float* Wk = (const float*)d_in[1];
  const float* Wq = (const float*)d_in[2];
  const float* W2 = (const float*)d_in[3];

  char* ws = (char*)d_ws;
  const size_t MB = 1024 * 1024;
  float* q    = (float*)(ws + 0);            //  2 MB  [4096,128] fp32
  float* k    = (float*)(ws + 2 * MB);       //  2 MB  [4096,128] fp32
  u16*   xT   = (u16*)  (ws + 4 * MB);       // 16 MB  [2048,4096] bf16
  u16*   W2b  = (u16*)  (ws + 20 * MB);      //  8 MB  [2048,2048] bf16
  u16*   outb = (u16*)  (ws + 28 * MB);      // 16 MB  [4096,2048] bf16
  u16*   attn = (u16*)  (ws + 44 * MB);      // 32 MB  [4096,4096] bf16
  float* S    = (float*)(ws + 76 * MB);      // 64 MB  [4096,4096] fp32
  float* outf = S;                           // 32 MB alias (scores dead after softmax)

  cast_f32_bf16<<<(2048 * 2048 / 4 + 255) / 256, 256, 0, stream>>>(W2, W2b, 2048 * 2048 / 4);
  transpose_cast<<<dim3(DMODEL / 64, NCTX / 64), 256, 0, stream>>>(x, xT);
  qk_proj<<<dim3(NCTX / 16, 2), 256, 0, stream>>>(x, Wq, Wk, q, k);
  scores_kernel<<<dim3(NCTX / 64, NCTX / 64), 256, 0, stream>>>(q, k, S);
  softmax_rows<<<NCTX, 256, 0, stream>>>(S, attn);
  gemm_bt<<<dim3(NCTX / 128, DMODEL / 128), 256, 0, stream>>>(attn, xT, outf,
                                                              NCTX, DMODEL, NCTX, 1);
  cast_f32_bf16<<<(NCTX * DMODEL / 4 + 255) / 256, 256, 0, stream>>>(outf, outb, NCTX * DMODEL / 4);
  gemm_bt<<<dim3(NCTX / 128, DMODEL / 128), 256, 0, stream>>>(outb, W2b, (float*)d_out,
                                                              NCTX, DMODEL, DMODEL, 0);
}

// Round 2
// 396.214 us; speedup vs baseline: 1.3676x; 1.3676x over previous
//
#include <hip/hip_runtime.h>

#define NCTX 4096
#define DMODEL 2048
#define DHEAD 128

typedef short s16x8 __attribute__((ext_vector_type(8)));
typedef float f32x4 __attribute__((ext_vector_type(4)));
typedef unsigned short u16;

__device__ __forceinline__ u16 f2bf(float f) {
  union { float f; unsigned u; } v; v.f = f;
  unsigned u = v.u;
  return (u16)((u + 0x7FFFu + ((u >> 16) & 1u)) >> 16);
}
__device__ __forceinline__ float bf2f(u16 h) {
  union { unsigned u; float f; } v; v.u = ((unsigned)h) << 16; return v.f;
}

__device__ __forceinline__ void gl_lds16(const void* g, void* l) {
  __builtin_amdgcn_global_load_lds((const __attribute__((address_space(1))) void*)g,
                                   (__attribute__((address_space(3))) void*)l, 16, 0, 0);
}

// ---------------- elementwise fp32 -> bf16 cast ----------------
__global__ __launch_bounds__(256) void cast_f32_bf16(const float* __restrict__ in,
                                                     u16* __restrict__ out, int n4) {
  int i = blockIdx.x * 256 + threadIdx.x;
  if (i >= n4) return;
  float4 v = ((const float4*)in)[i];
  ushort4 o;
  o.x = f2bf(v.x); o.y = f2bf(v.y); o.z = f2bf(v.z); o.w = f2bf(v.w);
  ((ushort4*)out)[i] = o;
}

// ---------------- fp32 -> (hi, lo) bf16 split ----------------
__global__ __launch_bounds__(256) void split_f32_bf16x2(const float* __restrict__ in,
                                                        u16* __restrict__ hi,
                                                        u16* __restrict__ lo, int n4) {
  int i = blockIdx.x * 256 + threadIdx.x;
  if (i >= n4) return;
  float4 v = ((const float4*)in)[i];
  ushort4 h, l;
  h.x = f2bf(v.x); l.x = f2bf(v.x - bf2f(h.x));
  h.y = f2bf(v.y); l.y = f2bf(v.y - bf2f(h.y));
  h.z = f2bf(v.z); l.z = f2bf(v.z - bf2f(h.z));
  h.w = f2bf(v.w); l.w = f2bf(v.w - bf2f(h.w));
  ((ushort4*)hi)[i] = h;
  ((ushort4*)lo)[i] = l;
}

// ---------------- x [4096,2048] fp32 -> xT [2048,4096] bf16 ----------------
__global__ __launch_bounds__(256) void transpose_cast(const float* __restrict__ X,
                                                      u16* __restrict__ XT) {
  __shared__ float tile[64][65];
  int db = blockIdx.x * 64, mb = blockIdx.y * 64;
  int tx = threadIdx.x & 63, ty = threadIdx.x >> 6;
#pragma unroll
  for (int r = 0; r < 16; ++r) {
    int row = ty * 16 + r;
    tile[row][tx] = X[(size_t)(mb + row) * DMODEL + db + tx];
  }
  __syncthreads();
#pragma unroll
  for (int r = 0; r < 16; ++r) {
    int row = ty * 16 + r;
    XT[(size_t)(db + row) * NCTX + mb + tx] = f2bf(tile[tx][row]);
  }
}

// ---------------- row softmax (fp32) -> bf16 attn, zero-fill j > i ----------------
__global__ __launch_bounds__(256) void softmax_rows(const float* __restrict__ S,
                                                    u16* __restrict__ P) {
  int i = blockIdx.x;
  int t = threadIdx.x;
  __shared__ float rowbuf[NCTX];
  __shared__ float red[4];
  __shared__ float red2[4];
  const float* srow = S + (size_t)i * NCTX;
  int len = i + 1;
  float mx = -3.0e38f;
  for (int j = t; j < len; j += 256) {
    float v = srow[j];
    rowbuf[j] = v;
    mx = fmaxf(mx, v);
  }
#pragma unroll
  for (int o = 32; o > 0; o >>= 1) mx = fmaxf(mx, __shfl_xor(mx, o, 64));
  if ((t & 63) == 0) red[t >> 6] = mx;
  __syncthreads();
  mx = fmaxf(fmaxf(red[0], red[1]), fmaxf(red[2], red[3]));
  float sum = 0.f;
  for (int j = t; j < len; j += 256) sum += __expf(rowbuf[j] - mx);
#pragma unroll
  for (int o = 32; o > 0; o >>= 1) sum += __shfl_xor(sum, o, 64);
  if ((t & 63) == 0) red2[t >> 6] = sum;
  __syncthreads();
  float inv = 1.0f / (red2[0] + red2[1] + red2[2] + red2[3]);
  u16* prow = P + (size_t)i * NCTX;
  for (int j = t; j < NCTX; j += 256) {
    float v = (j < len) ? __expf(rowbuf[j] - mx) * inv : 0.0f;
    prow[j] = f2bf(v);
  }
}

// ---------------- bf16 MFMA GEMM, B^T layout (single precision bf16) ----------------
// C[M,N] fp32 = A[M,K] (bf16 rm) * B[N,K]^T (bf16 rm). 128x128 tile, BK=32.
__global__ __launch_bounds__(256) void gemm_bt(const u16* __restrict__ A,
                                               const u16* __restrict__ B,
                                               float* __restrict__ C,
                                               int M, int N, int K, int causal) {
  __shared__ __align__(16) u16 As[128 * 32];
  __shared__ __align__(16) u16 Bs[128 * 32];
  int t = threadIdx.x;
  int lane = t & 63, w = t >> 6;
  int bm = blockIdx.x, bn = blockIdx.y;
  int m0 = bm * 128, n0 = bn * 128;
  int kEnd = K;
  if (causal) { int ke = (bm + 1) * 128; kEnd = ke < K ? ke : K; }
  int wm = (w >> 1) * 64, wn = (w & 1) * 64;
  int mfrag = lane & 15, quad = lane >> 4;
  int srow = t >> 2, schunk = t & 3;
  f32x4 acc[4][4] = {};
  for (int kt = 0; kt < kEnd; kt += 32) {
#pragma unroll
    for (int p = 0; p < 2; ++p) {
      int row = p * 64 + srow;
      gl_lds16(A + (size_t)(m0 + row) * K + kt + schunk * 8, As + (size_t)(p * 256 + t) * 8);
      gl_lds16(B + (size_t)(n0 + row) * K + kt + schunk * 8, Bs + (size_t)(p * 256 + t) * 8);
    }
    __syncthreads();
    s16x8 af[4], bfr[4];
#pragma unroll
    for (int i = 0; i < 4; ++i)
      af[i] = *(const s16x8*)(As + (wm + i * 16 + mfrag) * 32 + quad * 8);
#pragma unroll
    for (int j = 0; j < 4; ++j)
      bfr[j] = *(const s16x8*)(Bs + (wn + j * 16 + mfrag) * 32 + quad * 8);
#pragma unroll
    for (int i = 0; i < 4; ++i)
#pragma unroll
      for (int j = 0; j < 4; ++j)
        acc[i][j] = __builtin_amdgcn_mfma_f32_16x16x32_bf16(af[i], bfr[j], acc[i][j], 0, 0, 0);
    __syncthreads();
  }
#pragma unroll
  for (int i = 0; i < 4; ++i)
#pragma unroll
    for (int j = 0; j < 4; ++j)
#pragma unroll
      for (int rr = 0; rr < 4; ++rr) {
        int row = m0 + wm + i * 16 + quad * 4 + rr;
        int col = n0 + wn + j * 16 + mfrag;
        C[(size_t)row * N + col] = acc[i][j][rr];
      }
}

// ---------------- bf16x3 split-precision MFMA GEMM, B^T layout ----------------
// C = (Ah+Al) @ (Bh+Bl)^T  ~=  Ah@Bh^T + Al@Bh^T + Ah@Bl^T   (fp32-accurate)
// 128x128 tile, BK=32, strides lda/ldb/ldc in elements.
// causal: skip blocks with bn > bm (tile-level lower-triangular grid).
__global__ __launch_bounds__(256) void gemm_bt3(const u16* __restrict__ Ah,
                                                const u16* __restrict__ Al,
                                                const u16* __restrict__ Bh,
                                                const u16* __restrict__ Bl,
                                                float* __restrict__ C,
                                                int lda, int ldb, int ldc,
                                                int K, int causal) {
  int bm = blockIdx.x, bn = blockIdx.y;
  if (causal && bn > bm) return;
  __shared__ __align__(16) u16 Ash[128 * 32];
  __shared__ __align__(16) u16 Asl[128 * 32];
  __shared__ __align__(16) u16 Bsh[128 * 32];
  __shared__ __align__(16) u16 Bsl[128 * 32];
  int t = threadIdx.x;
  int lane = t & 63, w = t >> 6;
  int m0 = bm * 128, n0 = bn * 128;
  int wm = (w >> 1) * 64, wn = (w & 1) * 64;
  int mfrag = lane & 15, quad = lane >> 4;
  int srow = t >> 2, schunk = t & 3;
  f32x4 acc[4][4] = {};
  for (int kt = 0; kt < K; kt += 32) {
#pragma unroll
    for (int p = 0; p < 2; ++p) {
      int row = p * 64 + srow;
      size_t aoff = (size_t)(m0 + row) * lda + kt + schunk * 8;
      size_t boff = (size_t)(n0 + row) * ldb + kt + schunk * 8;
      size_t loff = (size_t)(p * 256 + t) * 8;
      gl_lds16(Ah + aoff, Ash + loff);
      gl_lds16(Al + aoff, Asl + loff);
      gl_lds16(Bh + boff, Bsh + loff);
      gl_lds16(Bl + boff, Bsl + loff);
    }
    __syncthreads();
    s16x8 a0[4], a1[4], b0[4];
#pragma unroll
    for (int i = 0; i < 4; ++i)
      a0[i] = *(const s16x8*)(Ash + (wm + i * 16 + mfrag) * 32 + quad * 8);
#pragma unroll
    for (int j = 0; j < 4; ++j)
      b0[j] = *(const s16x8*)(Bsh + (wn + j * 16 + mfrag) * 32 + quad * 8);
#pragma unroll
    for (int i = 0; i < 4; ++i)
#pragma unroll
      for (int j = 0; j < 4; ++j)
        acc[i][j] = __builtin_amdgcn_mfma_f32_16x16x32_bf16(a0[i], b0[j], acc[i][j], 0, 0, 0);
#pragma unroll
    for (int i = 0; i < 4; ++i)
      a1[i] = *(const s16x8*)(Asl + (wm + i * 16 + mfrag) * 32 + quad * 8);
#pragma unroll
    for (int i = 0; i < 4; ++i)
#pragma unroll
      for (int j = 0; j < 4; ++j)
        acc[i][j] = __builtin_amdgcn_mfma_f32_16x16x32_bf16(a1[i], b0[j], acc[i][j], 0, 0, 0);
#pragma unroll
    for (int j = 0; j < 4; ++j)
      b0[j] = *(const s16x8*)(Bsl + (wn + j * 16 + mfrag) * 32 + quad * 8);
#pragma unroll
    for (int i = 0; i < 4; ++i)
#pragma unroll
      for (int j = 0; j < 4; ++j)
        acc[i][j] = __builtin_amdgcn_mfma_f32_16x16x32_bf16(a0[i], b0[j], acc[i][j], 0, 0, 0);
    __syncthreads();
  }
#pragma unroll
  for (int i = 0; i < 4; ++i)
#pragma unroll
    for (int j = 0; j < 4; ++j)
#pragma unroll
      for (int rr = 0; rr < 4; ++rr) {
        int row = m0 + wm + i * 16 + quad * 4 + rr;
        int col = n0 + wn + j * 16 + mfrag;
        C[(size_t)row * ldc + col] = acc[i][j][rr];
      }
}

extern "C" void kernel_launch(void* const* d_in, const int* in_sizes, int n_in,
                              void* d_out, int out_size, void* d_ws, size_t ws_size,
                              hipStream_t stream) {
  const float* x  = (const float*)d_in[0];
  const float* Wk = (const float*)d_in[1];
  const float* Wq = (const float*)d_in[2];
  const float* W2 = (const float*)d_in[3];

  char* ws = (char*)d_ws;
  const size_t MB = 1024 * 1024;
  float* QK   = (float*)(ws + 0);            //  4 MB  [4096,256] fp32 (q | k)
  u16*   QKh  = (u16*)  (ws + 4 * MB);       //  2 MB
  u16*   QKl  = (u16*)  (ws + 6 * MB);       //  2 MB
  u16*   Wh   = (u16*)  (ws + 8 * MB);       //  1 MB  [256,2048] (Wq ; Wk) hi
  u16*   Wl   = (u16*)  (ws + 9 * MB);       //  1 MB  lo
  u16*   xT   = (u16*)  (ws + 10 * MB);      // 16 MB  [2048,4096] bf16
  u16*   W2b  = (u16*)  (ws + 26 * MB);      //  8 MB  [2048,2048] bf16
  u16*   outb = (u16*)  (ws + 34 * MB);      // 16 MB  [4096,2048] bf16
  u16*   attn = (u16*)  (ws + 50 * MB);      // 32 MB  [4096,4096] bf16
  u16*   xh   = (u16*)  (ws + 82 * MB);      // 16 MB  [4096,2048] bf16 (dead after qk gemm)
  u16*   xl   = (u16*)  (ws + 98 * MB);      // 16 MB  (dead after qk gemm)
  float* S    = (float*)(ws + 82 * MB);      // 64 MB  [4096,4096] fp32 — ALIASES xh/xl,
                                             //        written only after they are dead
  float* outf = S;                           // 32 MB alias (S dead after softmax)

  const int XN4 = NCTX * DMODEL / 4;
  const int WN4 = DHEAD * DMODEL / 4;
  const int QKN4 = NCTX * 256 / 4;

  // precision-critical path: bf16x3 splits
  split_f32_bf16x2<<<(XN4 + 255) / 256, 256, 0, stream>>>(x, xh, xl, XN4);
  split_f32_bf16x2<<<(WN4 + 255) / 256, 256, 0, stream>>>(Wq, Wh, Wl, WN4);
  split_f32_bf16x2<<<(WN4 + 255) / 256, 256, 0, stream>>>(Wk, Wh + (size_t)DHEAD * DMODEL,
                                                          Wl + (size_t)DHEAD * DMODEL, WN4);
  // bf16-precision operands for the post-softmax GEMMs
  cast_f32_bf16<<<(2048 * 2048 / 4 + 255) / 256, 256, 0, stream>>>(W2, W2b, 2048 * 2048 / 4);
  transpose_cast<<<dim3(DMODEL / 64, NCTX / 64), 256, 0, stream>>>(x, xT);

  // q,k = x @ [Wq;Wk]^T   (fp32-accurate via bf16x3)  [4096,256]
  gemm_bt3<<<dim3(NCTX / 128, 2), 256, 0, stream>>>(xh, xl, Wh, Wl, QK,
                                                    DMODEL, DMODEL, 256, DMODEL, 0);
  split_f32_bf16x2<<<(QKN4 + 255) / 256, 256, 0, stream>>>(QK, QKh, QKl, QKN4);

  // scores = q @ k^T (causal tiles), fp32-accurate
  gemm_bt3<<<dim3(NCTX / 128, NCTX / 128), 256, 0, stream>>>(QKh, QKl, QKh + DHEAD, QKl + DHEAD,
                                                             S, 256, 256, NCTX, DHEAD, 1);
  softmax_rows<<<NCTX, 256, 0, stream>>>(S, attn);

  // out = attn @ x  (causal K-limit), then @ W2^T
  gemm_bt<<<dim3(NCTX / 128, DMODEL / 128), 256, 0, stream>>>(attn, xT, outf,
                                                              NCTX, DMODEL, NCTX, 1);
  cast_f32_bf16<<<(XN4 + 255) / 256, 256, 0, stream>>>(outf, outb, XN4);
  gemm_bt<<<dim3(NCTX / 128, DMODEL / 128), 256, 0, stream>>>(outb, W2b, (float*)d_out,
                                                              NCTX, DMODEL, DMODEL, 0);
}